// Round 1
// baseline (246.604 us; speedup 1.0000x reference)
//
#include <hip/hip_runtime.h>
#include <hip/hip_bf16.h>
#include <math.h>

// Problem constants (B,S,H,M) = (8,128,768,128)
#define B_   8
#define S_   128
#define H_   768
#define M_   128
#define P_   8256      // S*(S+1)/2 pairs per batch
#define BP_  66048     // B_ * P_
#define EPSF 1e-12f

typedef unsigned short u16;
typedef unsigned int   u32;
typedef __bf16 bfrag  __attribute__((ext_vector_type(8)));
typedef float  f32x4  __attribute__((ext_vector_type(4)));

// ---- bf16 helpers (manual RNE pack, shift-unpack) ----
__device__ __forceinline__ float bflo(u32 u) { return __builtin_bit_cast(float, u << 16); }
__device__ __forceinline__ float bfhi(u32 u) { return __builtin_bit_cast(float, u & 0xffff0000u); }
__device__ __forceinline__ u32 f2bf(float f) {
    u32 u = __builtin_bit_cast(u32, f);
    return (u + 0x7fffu + ((u >> 16) & 1u)) >> 16;   // RNE
}
__device__ __forceinline__ u16 f2bfs(float f) { return (u16)f2bf(f); }
__device__ __forceinline__ u32 pack2(float lo, float hi) { return f2bf(lo) | (f2bf(hi) << 16); }
// shaking element pair: xn * gamma_c + beta_c  (two bf16 lanes in one u32)
__device__ __forceinline__ u32 fuse2(u32 x, u32 g, u32 b) {
    float rl = fmaf(bflo(x), bflo(g), bflo(b));
    float rh = fmaf(bfhi(x), bfhi(g), bfhi(b));
    return pack2(rl, rh);
}
__device__ __forceinline__ float fast_tanh(float v) {
    float e = __expf(-2.0f * fabsf(v));
    float t = (1.0f - e) / (1.0f + e);
    return copysignf(t, v);
}

// ============ kernel 0: convert weights to bf16; build WcT[n][h] ============
// wgb[o*768+h] = bf16(w_gamma[o][h]); wbb likewise.
// WcT[n*768+h] = bf16(w_{ent,head,tail}[h][n&127]) with head = n>>7  (B^T layout).
__global__ void k_convert(const float* __restrict__ wg, const float* __restrict__ wb,
                          const float* __restrict__ we, const float* __restrict__ wh,
                          const float* __restrict__ wt,
                          u16* __restrict__ wgb, u16* __restrict__ wbb, u16* __restrict__ wct)
{
    int idx = blockIdx.x * 256 + threadIdx.x;
    if (idx < 589824) {
        wgb[idx] = f2bfs(wg[idx]);
    } else if (idx < 1179648) {
        int i = idx - 589824;
        wbb[i] = f2bfs(wb[i]);
    } else {
        int i = idx - 1179648;              // [0, 294912)
        int n = i / 768, h = i - n * 768;
        const float* w = (n < 128) ? we : (n < 256 ? wh : wt);
        wct[i] = f2bfs(w[h * 128 + (n & 127)]);
    }
}

// ============ kernel 1: per-row normalize + seq->bf16 ============
// xn[row] = (x - mean) / (var + eps)^2   (reference squares, no sqrt!)
__global__ void k_norm(const float* __restrict__ seq, u16* __restrict__ xn, u16* __restrict__ condb)
{
    __shared__ float red[4];
    const int row = blockIdx.x;
    const int t = threadIdx.x;
    const int lane = t & 63, wid = t >> 6;
    const float* x = seq + (size_t)row * H_;
    float x0 = x[t], x1 = x[t + 256], x2 = x[t + 512];

    float s = x0 + x1 + x2;
    for (int o = 32; o; o >>= 1) s += __shfl_xor(s, o);
    if (lane == 0) red[wid] = s;
    __syncthreads();
    float mean = (red[0] + red[1] + red[2] + red[3]) * (1.0f / 768.0f);

    float c0 = x0 - mean, c1 = x1 - mean, c2 = x2 - mean;
    float ss = c0 * c0 + c1 * c1 + c2 * c2;
    for (int o = 32; o; o >>= 1) ss += __shfl_xor(ss, o);
    __syncthreads();
    if (lane == 0) red[wid] = ss;
    __syncthreads();
    float var = (red[0] + red[1] + red[2] + red[3]) * (1.0f / 768.0f);
    float sd = var + EPSF;
    float scale = 1.0f / (sd * sd);

    u16* xr = xn + (size_t)row * H_;
    u16* cr = condb + (size_t)row * H_;
    xr[t] = f2bfs(c0 * scale); xr[t + 256] = f2bfs(c1 * scale); xr[t + 512] = f2bfs(c2 * scale);
    cr[t] = f2bfs(x0);         cr[t + 256] = f2bfs(x1);         cr[t + 512] = f2bfs(x2);
}

// ============ kernel 2: cond GEMM -> gamma_c / beta_c (bf16) ============
// C[p][o] = sum_h cond[p][h] * W[o][h] + bias[o];   M=1024, N=2*768, K=768
// grid (8, 12): blockIdx.y<6 -> w_gamma/gamma/Gc ; else w_beta/beta/Bc
__global__ __launch_bounds__(256) void k_cond_gemm(
    const u16* __restrict__ Ab, const u16* __restrict__ Wg, const u16* __restrict__ Wb,
    const float* __restrict__ gamma, const float* __restrict__ beta,
    u16* __restrict__ Gc, u16* __restrict__ Bc)
{
    __shared__ u16 Ash[128 * 40];   // stride 40 (80B = 5x16B): conflict-free b128 reads
    __shared__ u16 Bsh[128 * 40];
    const int t = threadIdx.x;
    const int row0 = blockIdx.x * 128;
    const int cb = blockIdx.y;
    const bool isg = (cb < 6);
    const int nc0 = (isg ? cb : cb - 6) * 128;
    const u16* wsrc = isg ? Wg : Wb;

    const int r = t >> 1, half = t & 1;
    const u16* ap = Ab + (size_t)(row0 + r) * H_ + half * 16;
    const u16* wp = wsrc + (size_t)(nc0 + r) * H_ + half * 16;
    u16* asto = &Ash[r * 40 + half * 16];
    u16* bsto = &Bsh[r * 40 + half * 16];

    const int lane = t & 63, wid = t >> 6;
    const int wm0 = (wid >> 1) * 64, wn0 = (wid & 1) * 64;
    const int l15 = lane & 15, quad = lane >> 4, q8 = quad * 8;

    f32x4 acc[4][4] = {};
    for (int kt = 0; kt < 24; ++kt) {
        const int k0 = kt * 32;
        uint4 a0 = *(const uint4*)(ap + k0); uint4 a1 = *(const uint4*)(ap + k0 + 8);
        uint4 w0 = *(const uint4*)(wp + k0); uint4 w1 = *(const uint4*)(wp + k0 + 8);
        *(uint4*)asto = a0; *(uint4*)(asto + 8) = a1;
        *(uint4*)bsto = w0; *(uint4*)(bsto + 8) = w1;
        __syncthreads();
        bfrag af[4], bf[4];
#pragma unroll
        for (int mi = 0; mi < 4; ++mi)
            af[mi] = *reinterpret_cast<const bfrag*>(&Ash[(wm0 + mi * 16 + l15) * 40 + q8]);
#pragma unroll
        for (int ni = 0; ni < 4; ++ni)
            bf[ni] = *reinterpret_cast<const bfrag*>(&Bsh[(wn0 + ni * 16 + l15) * 40 + q8]);
#pragma unroll
        for (int mi = 0; mi < 4; ++mi)
#pragma unroll
            for (int ni = 0; ni < 4; ++ni)
                acc[mi][ni] = __builtin_amdgcn_mfma_f32_16x16x32_bf16(af[mi], bf[ni], acc[mi][ni], 0, 0, 0);
        __syncthreads();
    }

    const float* bias = isg ? gamma : beta;
    u16* outp = isg ? Gc : Bc;
#pragma unroll
    for (int mi = 0; mi < 4; ++mi)
#pragma unroll
        for (int ni = 0; ni < 4; ++ni) {
            int c = wn0 + ni * 16 + l15;
            float bv = bias[nc0 + c];
#pragma unroll
            for (int reg = 0; reg < 4; ++reg) {
                int rg = wm0 + mi * 16 + quad * 4 + reg;   // C/D: col=lane&15, row=quad*4+reg (m89)
                outp[(size_t)(row0 + rg) * H_ + nc0 + c] = f2bfs(acc[mi][ni][reg] + bv);
            }
        }
}

// ============ kernel 3: fused pair GEMM ============
// rows = global pair index gp in [0,66048): b=gp/8256, p=gp%8256 -> (i,j) triu
// A[gp][h] = xn[b,j,h]*Gc[b,i,h] + Bc[b,i,h]  (constructed in LDS, bf16)
// B = WcT (384x768), col-block cb in {0,1,2} = {ent,head,tail}
// out[(cb*66048 + gp)*128 + m] = tanh(dot + bias_cb[m])
__global__ __launch_bounds__(256) void k_pair_gemm(
    const u16* __restrict__ Xn, const u16* __restrict__ Gcb, const u16* __restrict__ Bcb,
    const u16* __restrict__ WcT,
    const float* __restrict__ b_ent, const float* __restrict__ b_head, const float* __restrict__ b_tail,
    float* __restrict__ out)
{
    __shared__ u16 Ash[128 * 40];
    __shared__ u16 Bsh[128 * 40];
    __shared__ int offx[128];   // xn row index (b*128 + j)
    __shared__ int offc[128];   // cond row index (b*128 + i)

    const int t = threadIdx.x;
    const int row0 = blockIdx.x * 128;
    const int cb = blockIdx.y;

    if (t < 128) {
        int gp = row0 + t;
        int b = gp / P_;
        int p = gp - b * P_;
        // invert p -> i:  off(i) = i*(257-i)/2 ;  i = floor((257 - sqrt(257^2 - 8p))/2) + fixup
        int i = (int)((257.0f - sqrtf(66049.0f - 8.0f * (float)p)) * 0.5f);
        if (i < 0) i = 0; if (i > 127) i = 127;
        while (i > 0 && (i * (257 - i)) / 2 > p) --i;
        while (((i + 1) * (256 - i)) / 2 <= p) ++i;
        int j = i + (p - (i * (257 - i)) / 2);
        offx[t] = b * 128 + j;
        offc[t] = b * 128 + i;
    }
    __syncthreads();

    const int r = t >> 1, half = t & 1;
    const u16* xp = Xn + (size_t)offx[r] * H_ + half * 16;
    const u16* gp_ = Gcb + (size_t)offc[r] * H_ + half * 16;
    const u16* bp_ = Bcb + (size_t)offc[r] * H_ + half * 16;
    const u16* wp = WcT + (size_t)(cb * 128 + r) * H_ + half * 16;
    u16* asto = &Ash[r * 40 + half * 16];
    u16* bsto = &Bsh[r * 40 + half * 16];

    const int lane = t & 63, wid = t >> 6;
    const int wm0 = (wid >> 1) * 64, wn0 = (wid & 1) * 64;
    const int l15 = lane & 15, quad = lane >> 4, q8 = quad * 8;

    f32x4 acc[4][4] = {};
    for (int kt = 0; kt < 24; ++kt) {
        const int k0 = kt * 32;
        uint4 xv0 = *(const uint4*)(xp + k0);  uint4 xv1 = *(const uint4*)(xp + k0 + 8);
        uint4 gv0 = *(const uint4*)(gp_ + k0); uint4 gv1 = *(const uint4*)(gp_ + k0 + 8);
        uint4 bv0 = *(const uint4*)(bp_ + k0); uint4 bv1 = *(const uint4*)(bp_ + k0 + 8);
        uint4 wv0 = *(const uint4*)(wp + k0);  uint4 wv1 = *(const uint4*)(wp + k0 + 8);
        uint4 av0, av1;
        av0.x = fuse2(xv0.x, gv0.x, bv0.x); av0.y = fuse2(xv0.y, gv0.y, bv0.y);
        av0.z = fuse2(xv0.z, gv0.z, bv0.z); av0.w = fuse2(xv0.w, gv0.w, bv0.w);
        av1.x = fuse2(xv1.x, gv1.x, bv1.x); av1.y = fuse2(xv1.y, gv1.y, bv1.y);
        av1.z = fuse2(xv1.z, gv1.z, bv1.z); av1.w = fuse2(xv1.w, gv1.w, bv1.w);
        *(uint4*)asto = av0; *(uint4*)(asto + 8) = av1;
        *(uint4*)bsto = wv0; *(uint4*)(bsto + 8) = wv1;
        __syncthreads();
        bfrag af[4], bf[4];
#pragma unroll
        for (int mi = 0; mi < 4; ++mi)
            af[mi] = *reinterpret_cast<const bfrag*>(&Ash[(wm0 + mi * 16 + l15) * 40 + q8]);
#pragma unroll
        for (int ni = 0; ni < 4; ++ni)
            bf[ni] = *reinterpret_cast<const bfrag*>(&Bsh[(wn0 + ni * 16 + l15) * 40 + q8]);
#pragma unroll
        for (int mi = 0; mi < 4; ++mi)
#pragma unroll
            for (int ni = 0; ni < 4; ++ni)
                acc[mi][ni] = __builtin_amdgcn_mfma_f32_16x16x32_bf16(af[mi], bf[ni], acc[mi][ni], 0, 0, 0);
        __syncthreads();
    }

    const float* bias = (cb == 0) ? b_ent : (cb == 1 ? b_head : b_tail);
#pragma unroll
    for (int mi = 0; mi < 4; ++mi)
#pragma unroll
        for (int ni = 0; ni < 4; ++ni) {
            int c = wn0 + ni * 16 + l15;
            float bv = bias[c];
#pragma unroll
            for (int reg = 0; reg < 4; ++reg) {
                int rg = wm0 + mi * 16 + quad * 4 + reg;
                size_t gp2 = (size_t)row0 + rg;
                out[((size_t)cb * BP_ + gp2) * M_ + c] = fast_tanh(acc[mi][ni][reg] + bv);
            }
        }
}

extern "C" void kernel_launch(void* const* d_in, const int* in_sizes, int n_in,
                              void* d_out, int out_size, void* d_ws, size_t ws_size,
                              hipStream_t stream)
{
    const float* seq     = (const float*)d_in[0];
    const float* gamma   = (const float*)d_in[1];
    const float* beta    = (const float*)d_in[2];
    const float* w_beta  = (const float*)d_in[3];
    const float* w_gamma = (const float*)d_in[4];
    const float* w_ent   = (const float*)d_in[5];
    const float* b_ent   = (const float*)d_in[6];
    const float* w_head  = (const float*)d_in[7];
    const float* b_head  = (const float*)d_in[8];
    const float* w_tail  = (const float*)d_in[9];
    const float* b_tail  = (const float*)d_in[10];
    float* out = (float*)d_out;

    // workspace layout (all 16B-aligned)
    char* ws = (char*)d_ws;
    u16* xn    = (u16*)ws; ws += (size_t)1024 * 768 * 2;  // normalized rows, bf16
    u16* condb = (u16*)ws; ws += (size_t)1024 * 768 * 2;  // seq as bf16
    u16* wgb   = (u16*)ws; ws += (size_t)768 * 768 * 2;   // w_gamma bf16 [o][h]
    u16* wbb   = (u16*)ws; ws += (size_t)768 * 768 * 2;   // w_beta  bf16 [o][h]
    u16* wct   = (u16*)ws; ws += (size_t)384 * 768 * 2;   // [n][h] combined ent|head|tail
    u16* gc    = (u16*)ws; ws += (size_t)1024 * 768 * 2;  // gamma_c bf16
    u16* bc    = (u16*)ws; ws += (size_t)1024 * 768 * 2;  // beta_c  bf16

    hipLaunchKernelGGL(k_convert, dim3(5760), dim3(256), 0, stream,
                       w_gamma, w_beta, w_ent, w_head, w_tail, wgb, wbb, wct);
    hipLaunchKernelGGL(k_norm, dim3(1024), dim3(256), 0, stream, seq, xn, condb);
    hipLaunchKernelGGL(k_cond_gemm, dim3(8, 12), dim3(256), 0, stream,
                       condb, wgb, wbb, gamma, beta, gc, bc);
    hipLaunchKernelGGL(k_pair_gemm, dim3(516, 3), dim3(256), 0, stream,
                       xn, gc, bc, wct, b_ent, b_head, b_tail, out);
}